// Round 10
// baseline (21599.486 us; speedup 1.0000x reference)
//
#include <hip/hip_runtime.h>
#include <cstdint>
#include <cstddef>

#define SEQ   8192
#define HD    2048
#define IND   16
#define NBLK  256   // one block per CU; each owns 8 hidden units
#define NTHR  320   // waves 0..3 compute (R9 structure), wave 4 = comm wave
#define NSLOT 1024  // u64 slots per parity: lo32 = 2xfp16 h-pair, hi32 = tag
#define NXCD  8

typedef _Float16 h2  __attribute__((ext_vector_type(2)));
typedef unsigned u32x4 __attribute__((ext_vector_type(4)));

union paircvt { h2 v; unsigned u; };

__device__ __forceinline__ float fdot2f(h2 a, h2 b, float c) {
#if defined(__has_builtin)
#if __has_builtin(__builtin_amdgcn_fdot2)
    return __builtin_amdgcn_fdot2(a, b, c, false);
#else
    return c + (float)a.x * (float)b.x + (float)a.y * (float)b.y;
#endif
#else
    return c + (float)a.x * (float)b.x + (float)a.y * (float)b.y;
#endif
}

__device__ __forceinline__ float sigmoid_f(float x) {
    return 1.f / (1.f + __expf(-x));
}
__device__ __forceinline__ float tanh_f(float x) {
    float e = __expf(2.f * x);
    return 1.f - 2.f / (e + 1.f);
}

__device__ __forceinline__ unsigned my_xcd() {
    unsigned x;
    asm volatile("s_getreg_b32 %0, hwreg(HW_REG_XCC_ID, 0, 4)" : "=s"(x));
    return x & (NXCD - 1);
}

// Persistent LSTM, round 10: DEDICATED COMM WAVE.
// R9's publisher wave issued 8 replica stores + 1 hs16 store, then its t+1
// poll's s_waitcnt vmcnt(0) (per-wave, in-order) had to drain all 9 store
// ACKS (~500-700 cyc) before evaluating the first poll load — every step,
// every wave. Here waves 0..3 compute (R9 verbatim) and hand gate outputs
// to LDS mailboxes (volatile value-then-tag; DS pipe is in-order per
// wave), then go STRAIGHT to the t+1 poll with a clean vmcnt. Wave 4
// spins on the mailboxes (LDS only) and publishes all 4 slots x 8
// replicas in one exec-masked 32-lane store + the hs16 history store;
// all store-ack latency lives on wave 4, off the critical path.
// Barriers stay matched (comm does one __syncthreads per step; s_barrier
// is arrival-count based). Deadlock-free: comm spins on own-block LDS;
// compute spins on replicas fed by co-resident comm waves.
__global__ __launch_bounds__(NTHR, 1) void lstm_persist(
    const float* __restrict__ sa,    // [SEQ, IND]
    const float* __restrict__ W_ih,  // [4*HD, IND]
    const float* __restrict__ W_hh,  // [4*HD, HD]
    const float* __restrict__ b_ih,  // [4*HD]
    const float* __restrict__ b_hh,  // [4*HD]
    unsigned long long* __restrict__ hrep,  // [NXCD][2][NSLOT] replicas
    _Float16* __restrict__ hs16)     // [SEQ, HD] h history (fp16)
{
    const int b   = blockIdx.x;
    const int tid = threadIdx.x;
    const int w   = tid >> 6;        // wave 0..4
    const int L   = tid & 63;        // lane
    const unsigned xcd = my_xcd();

    __shared__ h2 hh2[16 * 64];      // h_t pairs, XOR-swizzled [k][row^2k]
    __shared__ volatile unsigned mval[4];  // mailbox: packed h2 pair
    __shared__ volatile unsigned mtag[4];  // mailbox: step tag (t+1)

    if (tid < 4) mtag[tid] = 0;      // LDS is NOT zero-initialized
    __syncthreads();

    // ================= COMM WAVE =================
    if (w == 4) {
        const int j = L & 3;         // slot within block
        const int x = L >> 2;        // replica (L<32)
        for (unsigned t = 0; t < SEQ; ++t) {
            __syncthreads();         // matches compute's stage barrier
            // spin on own-block mailboxes (LDS only, cheap)
            while (mtag[j] != t + 1) { __builtin_amdgcn_s_sleep(1); }
            const unsigned v = mval[j];   // ordered: tag written after val
            const unsigned pout = (t + 1) & 1;
            const unsigned long long msg =
                ((unsigned long long)(t + 1) << 32) | (unsigned long long)v;
            if (L < 32)              // one 32-lane store: 4 slots x 8 replicas
                __hip_atomic_store(
                    &hrep[((size_t)x * 2 + pout) * NSLOT + (size_t)b * 4 + j],
                    msg, __ATOMIC_RELAXED, __HIP_MEMORY_SCOPE_AGENT);
            if (L < 4)               // h history (off critical path)
                ((unsigned*)hs16)[(size_t)t * (HD / 2) + b * 4 + L] = v;
        }
        return;
    }

    // ================= COMPUTE WAVES (R9 verbatim core) =================
    const int ubase = b * 8 + 2 * w; // first of this wave's 2 units

    // ---- one-time: W_hh fragment -> registers (fp16 pairs) ----
    // 8 rows (r: gate=r&3, unit=r>>2), lane L owns cols [32L, 32L+32)
    h2 wreg[8][16];
#pragma unroll
    for (int r = 0; r < 8; ++r) {
        const int row = (r & 3) * HD + ubase + (r >> 2);
        const float4* Wr = (const float4*)(W_hh + (size_t)row * HD + L * 32);
#pragma unroll
        for (int q = 0; q < 8; ++q) {
            float4 f = Wr[q];
            h2 lo; lo.x = (_Float16)f.x; lo.y = (_Float16)f.y;
            h2 hi; hi.x = (_Float16)f.z; hi.y = (_Float16)f.w;
            wreg[r][2 * q]     = lo;
            wreg[r][2 * q + 1] = hi;
        }
    }
    // W_ih row + bias for the row this lane ends up holding (r = L&7)
    const int rowL = (L & 3) * HD + ubase + ((L >> 2) & 1);
    float wih[IND];
    {
        const float4* Wi = (const float4*)(W_ih + (size_t)rowL * IND);
#pragma unroll
        for (int q = 0; q < 4; ++q) {
            float4 f = Wi[q];
            wih[4 * q]     = f.x;
            wih[4 * q + 1] = f.y;
            wih[4 * q + 2] = f.z;
            wih[4 * q + 3] = f.w;
        }
    }
    const float bias = b_ih[rowL] + b_hh[rowL];

    // cell state: lanes with (L&4)==0 hold c of unit0, (L&4)==4 -> unit1
    float c = 0.f;

    for (unsigned t = 0; t < SEQ; ++t) {
        // ---- xp precompute (h-independent): hidden under the poll ----
        float xp = bias;
        {
            const float* sat = sa + (size_t)t * IND;
#pragma unroll
            for (int k = 0; k < IND; ++k) xp += sat[k] * wih[k];
        }

        // ---- poll own-XCD replica (sc1); vmcnt is CLEAN (no stores) ----
        const unsigned pin = t & 1;
        const uint32_t* base =
            (const uint32_t*)(hrep + ((size_t)xcd * 2 + pin) * NSLOT);
        const uint32_t* pp0 = base + 4 * tid;
        const uint32_t* pp1 = base + 1024 + 4 * tid;
        u32x4 m0, m1;
        for (;;) {
            asm volatile(
                "global_load_dwordx4 %0, %2, off sc1\n\t"
                "global_load_dwordx4 %1, %3, off sc1\n\t"
                "s_waitcnt vmcnt(0)"
                : "=v"(m0), "=v"(m1)
                : "v"(pp0), "v"(pp1) : "memory");
            bool ok = (m0.y == t) & (m0.w == t) & (m1.y == t) & (m1.w == t);
            if (ok) break;
            __builtin_amdgcn_s_sleep(1);
        }

        // ---- stage 4 pairs into swizzled LDS (<=2-way = free) ----
        {
            paircvt cv;
            const int pa = 2 * tid, pb = 2 * tid + 1;
            const int pc = 512 + 2 * tid, pd = 513 + 2 * tid;
            cv.u = m0.x;
            hh2[(pa & 15) * 64 + (((pa >> 4) ^ (2 * (pa & 15))) & 63)] = cv.v;
            cv.u = m0.z;
            hh2[(pb & 15) * 64 + (((pb >> 4) ^ (2 * (pb & 15))) & 63)] = cv.v;
            cv.u = m1.x;
            hh2[(pc & 15) * 64 + (((pc >> 4) ^ (2 * (pc & 15))) & 63)] = cv.v;
            cv.u = m1.z;
            hh2[(pd & 15) * 64 + (((pd >> 4) ^ (2 * (pd & 15))) & 63)] = cv.v;
        }
        __syncthreads();

        // ---- read this lane's 16 pairs (cols [32L, 32L+32)) ----
        h2 hv[16];
#pragma unroll
        for (int k = 0; k < 16; ++k)
            hv[k] = hh2[k * 64 + ((L ^ (2 * k)) & 63)];

        // ---- 8 rows x 32 cols of dot product per lane ----
        float p[8] = {0.f, 0.f, 0.f, 0.f, 0.f, 0.f, 0.f, 0.f};
#pragma unroll
        for (int r = 0; r < 8; ++r)
#pragma unroll
            for (int k = 0; k < 16; ++k)
                p[r] = fdot2f(wreg[r][k], hv[k], p[r]);

        // ---- merge-reduce: lane L ends with full sum of row (L&7) ----
        const bool h1 = (L & 1), h2b = (L & 2), h4 = (L & 4);
        float v0, v1, v2, v3;
        {
            float k0 = h1 ? p[1] : p[0], s0 = h1 ? p[0] : p[1];
            v0 = k0 + __shfl_xor(s0, 1, 64);
            float k1 = h1 ? p[3] : p[2], s1 = h1 ? p[2] : p[3];
            v1 = k1 + __shfl_xor(s1, 1, 64);
            float k2 = h1 ? p[5] : p[4], s2 = h1 ? p[4] : p[5];
            v2 = k2 + __shfl_xor(s2, 1, 64);
            float k3 = h1 ? p[7] : p[6], s3 = h1 ? p[6] : p[7];
            v3 = k3 + __shfl_xor(s3, 1, 64);
        }
        float w0, w1;
        {
            float k0 = h2b ? v1 : v0, s0 = h2b ? v0 : v1;
            w0 = k0 + __shfl_xor(s0, 2, 64);
            float k1 = h2b ? v3 : v2, s1 = h2b ? v2 : v3;
            w1 = k1 + __shfl_xor(s1, 2, 64);
        }
        float tot;
        {
            float k0 = h4 ? w1 : w0, s0 = h4 ? w0 : w1;
            tot = k0 + __shfl_xor(s0, 4, 64);
        }
        tot += __shfl_xor(tot, 8, 64);
        tot += __shfl_xor(tot, 16, 64);
        tot += __shfl_xor(tot, 32, 64);
        tot += xp;

        // ---- gates: all intra-wave (width-8 shuffles) ----
        const int ub4 = L & 4;   // 0 -> unit0 rows 0..3, 4 -> unit1 rows 4..7
        float gi = __shfl(tot, ub4 + 0, 8);
        float gf = __shfl(tot, ub4 + 1, 8);
        float gg = __shfl(tot, ub4 + 2, 8);
        float go = __shfl(tot, ub4 + 3, 8);
        float ii = sigmoid_f(gi);
        float ff = sigmoid_f(gf);
        float g  = tanh_f(gg);
        float oo = sigmoid_f(go);
        c = ff * c + ii * g;
        float h = oo * tanh_f(c);
        float hO = __shfl_xor(h, 4, 64);   // lane0: unit1's h (from lane4)

        // ---- hand off to comm wave: value FIRST, then tag (in-order) ----
        if (L == 0) {
            paircvt pk;
            pk.v.x = (_Float16)h;    // unit ubase
            pk.v.y = (_Float16)hO;   // unit ubase+1
            mval[w] = pk.u;
            mtag[w] = t + 1;
        }
        // straight to t+1 poll: no stores on this wave's vmcnt
    }
}

// Output projection: out[t,0:3] = hs[t]·W_uvw^T + b_uvw,
//                    out[t,3:6] = hs[t]·W_pqr^T + b_pqr
__global__ __launch_bounds__(256) void out_proj_kernel(
    const _Float16* __restrict__ hs16,
    const float* __restrict__ W_uvw, const float* __restrict__ b_uvw,
    const float* __restrict__ W_pqr, const float* __restrict__ b_pqr,
    float* __restrict__ out)
{
    __shared__ float Ws[6 * HD];
    const int tid = threadIdx.x;
    for (int i = tid; i < 3 * HD; i += 256) Ws[i] = W_uvw[i];
    for (int i = tid; i < 3 * HD; i += 256) Ws[3 * HD + i] = W_pqr[i];
    __syncthreads();

    const int w = tid >> 6, L = tid & 63;
#pragma unroll
    for (int r = 0; r < 4; ++r) {
        const int t = blockIdx.x * 16 + w * 4 + r;
        const _Float16* hrow = hs16 + (size_t)t * HD;
        float acc[6] = {0.f, 0.f, 0.f, 0.f, 0.f, 0.f};
        for (int cidx = L; cidx < HD; cidx += 64) {
            float hval = (float)hrow[cidx];
#pragma unroll
            for (int j = 0; j < 6; ++j) acc[j] += hval * Ws[j * HD + cidx];
        }
#pragma unroll
        for (int j = 0; j < 6; ++j) {
#pragma unroll
            for (int d = 1; d < 64; d <<= 1)
                acc[j] += __shfl_xor(acc[j], d, 64);
        }
        if (L == 0) {
#pragma unroll
            for (int j = 0; j < 6; ++j)
                out[(size_t)t * 6 + j] =
                    acc[j] + (j < 3 ? b_uvw[j] : b_pqr[j - 3]);
        }
    }
}

extern "C" void kernel_launch(void* const* d_in, const int* in_sizes, int n_in,
                              void* d_out, int out_size, void* d_ws, size_t ws_size,
                              hipStream_t stream) {
    (void)in_sizes; (void)n_in; (void)out_size; (void)ws_size;

    const float* sa    = (const float*)d_in[0];
    const float* W_ih  = (const float*)d_in[1];
    const float* W_hh  = (const float*)d_in[2];
    const float* b_ih  = (const float*)d_in[3];
    const float* b_hh  = (const float*)d_in[4];
    const float* W_uvw = (const float*)d_in[5];
    const float* b_uvw = (const float*)d_in[6];
    const float* W_pqr = (const float*)d_in[7];
    const float* b_pqr = (const float*)d_in[8];
    float* out = (float*)d_out;

    // workspace: [hs16: 32 MB][hrep: NXCD*2*NSLOT*8 = 128 KB]
    char* ws = (char*)d_ws;
    _Float16* hs16 = (_Float16*)ws;
    unsigned long long* hrep =
        (unsigned long long*)(ws + (size_t)SEQ * HD * 2);

    // zero replicas: tag 0 == "h_0 = 0 is ready" in every copy
    hipMemsetAsync(hrep, 0, (size_t)NXCD * 2 * NSLOT * 8, stream);

    hipLaunchKernelGGL(lstm_persist, dim3(NBLK), dim3(NTHR), 0, stream,
                       sa, W_ih, W_hh, b_ih, b_hh, hrep, hs16);
    hipLaunchKernelGGL(out_proj_kernel, dim3(SEQ / 16), dim3(256), 0, stream,
                       hs16, W_uvw, b_uvw, W_pqr, b_pqr, out);
}